// Round 3
// baseline (3728.720 us; speedup 1.0000x reference)
//
#include <hip/hip_runtime.h>
#include <math.h>

#define NB 16
#define NHW 3136
#define NROWS 50176          // 16*56*56
#define CD 384
#define CH2 192
#define SCL 0.20412414523193154f   // 24^-0.5

static __device__ __forceinline__ float gelu_exact(float v) {
  return 0.5f * v * (1.0f + erff(v * 0.70710678118654752440f));
}

// ---------------- LayerNorm (one wave per row) ----------------
template<int CN>
__global__ __launch_bounds__(256) void ln_k(const float* __restrict__ x,
    const float* __restrict__ w, const float* __restrict__ b,
    float* __restrict__ out)
{
  constexpr int NPER = CN / 64;
  int wave = threadIdx.x >> 6, lane = threadIdx.x & 63;
  int row = blockIdx.x * 4 + wave;
  const float* xp = x + (size_t)row * CN;
  float v[NPER];
  float s = 0.f;
  #pragma unroll
  for (int i = 0; i < NPER; i++) { v[i] = xp[lane + 64*i]; s += v[i]; }
  #pragma unroll
  for (int off = 32; off; off >>= 1) s += __shfl_xor(s, off);
  float mean = s * (1.0f / CN);
  float vs = 0.f;
  #pragma unroll
  for (int i = 0; i < NPER; i++) { float d = v[i] - mean; vs += d*d; }
  #pragma unroll
  for (int off = 32; off; off >>= 1) vs += __shfl_xor(vs, off);
  float rstd = rsqrtf(vs * (1.0f / CN) + 1e-6f);
  float* op = out + (size_t)row * CN;
  #pragma unroll
  for (int i = 0; i < NPER; i++) {
    int c = lane + 64*i;
    op[c] = (v[i] - mean) * rstd * w[c] + b[c];
  }
}

// ---------------- 8x8 average pool of concat(xn, xen) ----------------
__global__ void pool_k(const float* __restrict__ xn, const float* __restrict__ xen,
                       float* __restrict__ pooled)
{
  int c = threadIdx.x;           // 0..575
  int blk = blockIdx.x;          // 0..783
  int b = blk / 49, q = blk % 49;
  int py = q / 7, px = q % 7;
  float s = 0.f;
  if (c < CD) {
    const float* base = xn + (((size_t)(b*56 + py*8))*56 + px*8) * CD + c;
    #pragma unroll
    for (int iy = 0; iy < 8; iy++)
      for (int ix = 0; ix < 8; ix++)
        s += base[(iy*56 + ix) * CD];
  } else {
    int cc = c - CD;
    const float* base = xen + (((size_t)(b*56 + py*8))*56 + px*8) * CH2 + cc;
    #pragma unroll
    for (int iy = 0; iy < 8; iy++)
      for (int ix = 0; ix < 8; ix++)
        s += base[(iy*56 + ix) * CH2];
  }
  pooled[(size_t)blk * 576 + c] = s * (1.0f / 64.0f);
}

// ---------------- fp32 tiled GEMM: 256x128 tile, 16x8/thread ----------------
// Bs column swizzle: +4-float pad every 32 floats -> all inner-loop LDS read
// conflicts are 2-way (free on CDNA4).
#define SWZ(c) ((c) + (((c) >> 5) << 2))

template<int MODE>
__global__ __launch_bounds__(256) void gemm_k(
    const float* __restrict__ A, int lda,
    const float* __restrict__ B, int ldb,
    const float* __restrict__ bias,
    float* __restrict__ C, int ldc,
    int M, int N, int K)
{
  __shared__ float As[16][260];   // [k][m]        16.6 KB
  __shared__ float Bs[16][144];   // [k][swz(col)]  9.2 KB
  const int tid = threadIdx.x;
  const int tx = tid & 15;        // col group (8 cols)
  const int ty = tid >> 4;        // row group (16 rows)
  const int mbase = blockIdx.y * 256;
  const int nbase = blockIdx.x * 128;

  const int am = tid;             // A row in tile
  const int bk = tid >> 4;        // B k-row
  const int bc = (tid & 15) * 8;  // B col in tile

  const bool aok = (mbase + am) < M;
  const bool bok = (nbase + bc) < N;   // N,bc multiples of 8 -> whole 8-col slab
  const float4 f4z = {0.f, 0.f, 0.f, 0.f};

  float4 ar[4], br[2];
  {
    const float* ap = A + (size_t)(mbase + am) * lda;
    #pragma unroll
    for (int j = 0; j < 4; j++) ar[j] = aok ? *(const float4*)(ap + 4*j) : f4z;
    const float* bp = B + (size_t)bk * ldb + nbase + bc;
    br[0] = bok ? *(const float4*)(bp)     : f4z;
    br[1] = bok ? *(const float4*)(bp + 4) : f4z;
  }

  float acc[16][8] = {};
  const int aoff = ty * 16;
  const int boff0 = SWZ(tx*8), boff1 = SWZ(tx*8 + 4);

  for (int k0 = 0; k0 < K; k0 += 16) {
    #pragma unroll
    for (int j = 0; j < 4; j++) {
      As[4*j+0][am] = ar[j].x; As[4*j+1][am] = ar[j].y;
      As[4*j+2][am] = ar[j].z; As[4*j+3][am] = ar[j].w;
    }
    *(float4*)&Bs[bk][SWZ(bc)]     = br[0];
    *(float4*)&Bs[bk][SWZ(bc + 4)] = br[1];
    __syncthreads();
    if (k0 + 16 < K) {
      const float* ap = A + (size_t)(mbase + am) * lda + k0 + 16;
      #pragma unroll
      for (int j = 0; j < 4; j++) ar[j] = aok ? *(const float4*)(ap + 4*j) : f4z;
      const float* bp = B + (size_t)(k0 + 16 + bk) * ldb + nbase + bc;
      br[0] = bok ? *(const float4*)(bp)     : f4z;
      br[1] = bok ? *(const float4*)(bp + 4) : f4z;
    }
    #pragma unroll
    for (int k = 0; k < 16; k++) {
      float b0[8];
      *(float4*)&b0[0] = *(const float4*)&Bs[k][boff0];
      *(float4*)&b0[4] = *(const float4*)&Bs[k][boff1];
      #pragma unroll
      for (int ii = 0; ii < 4; ii++) {
        float4 a4 = *(const float4*)&As[k][aoff + 4*ii];
        float av[4] = {a4.x, a4.y, a4.z, a4.w};
        #pragma unroll
        for (int t = 0; t < 4; t++)
          #pragma unroll
          for (int j = 0; j < 8; j++)
            acc[ii*4 + t][j] += av[t] * b0[j];
      }
    }
    __syncthreads();
  }

  float bv[8];
  #pragma unroll
  for (int j = 0; j < 8; j++)
    bv[j] = (nbase + tx*8 + j) < N ? bias[nbase + tx*8 + j] : 0.f;
  if (bok) {
    #pragma unroll
    for (int i = 0; i < 16; i++) {
      int m = mbase + ty*16 + i;
      if (m < M) {
        float* cp = &C[(size_t)m * ldc + nbase + tx*8];
        float v[8];
        #pragma unroll
        for (int j = 0; j < 8; j++) {
          v[j] = acc[i][j] + bv[j];
          if (MODE == 1) v[j] = gelu_exact(v[j]);
          if (MODE == 2) v[j] = cp[j] * v[j];
        }
        *(float4*)(cp)     = *(float4*)&v[0];
        *(float4*)(cp + 4) = *(float4*)&v[4];
      }
    }
  }
}

// ---------------- depthwise 7x7 conv, pad 3, NHWC — LDS-tiled ----------------
template<int CH>
__global__ __launch_bounds__(256) void dwconv_k(const float* __restrict__ in,
    const float* __restrict__ wgt, const float* __restrict__ bias,
    float* __restrict__ out)
{
  __shared__ float in_t[196 * 64];   // [pos=iy*14+ix][c]
  __shared__ float wlds[64 * 49];    // [c*49+tap]

  const int t = threadIdx.x;
  const int c = t & 63;
  const int pg = t >> 6;
  const int tile = blockIdx.x;       // 0..48
  const int cbase = blockIdx.y * 64;
  const int b = blockIdx.z;
  const int oy0 = (tile / 7) * 8;
  const int ox0 = (tile % 7) * 8;

  #pragma unroll 7
  for (int i = 0; i < 49; i++) {
    int p = pg + 4 * i;
    int iy = p / 14, ix = p % 14;
    int gy = oy0 + iy - 3;
    int gx = ox0 + ix - 3;
    float v = 0.f;
    if ((unsigned)gy < 56u && (unsigned)gx < 56u)
      v = in[((size_t)(b * 56 + gy) * 56 + gx) * CH + cbase + c];
    in_t[p * 64 + c] = v;
  }
  #pragma unroll
  for (int i = 0; i < 13; i++) {
    int j = t + 256 * i;
    if (j < 64 * 49) wlds[j] = wgt[(size_t)cbase * 49 + j];
  }
  __syncthreads();

  float bv = bias[cbase + c];
  float acc[2][8];
  #pragma unroll
  for (int r = 0; r < 2; r++)
    #pragma unroll
    for (int x = 0; x < 8; x++) acc[r][x] = bv;

  #pragma unroll
  for (int dy = 0; dy < 7; dy++) {
    float wrow[7];
    #pragma unroll
    for (int dx = 0; dx < 7; dx++) wrow[dx] = wlds[c * 49 + dy * 7 + dx];
    #pragma unroll
    for (int r = 0; r < 2; r++) {
      int oy = pg * 2 + r;
      int iy = oy + dy;
      float win[14];
      #pragma unroll
      for (int j = 0; j < 14; j++) win[j] = in_t[(iy * 14 + j) * 64 + c];
      #pragma unroll
      for (int dx = 0; dx < 7; dx++)
        #pragma unroll
        for (int x = 0; x < 8; x++)
          acc[r][x] += win[x + dx] * wrow[dx];
    }
  }

  #pragma unroll
  for (int r = 0; r < 2; r++) {
    int oy = pg * 2 + r;
    #pragma unroll
    for (int x = 0; x < 8; x++) {
      out[((size_t)(b * 56 + oy0 + oy) * 56 + ox0 + x) * CH + cbase + c] = acc[r][x];
    }
  }
}

// ---------------- attention part 1: per-chunk online softmax partials ----------------
// grid (128 bh, 8 chunks) x 256. Each wave: 98 keys. part[(bh*8+chunk)][q][26]
__global__ __launch_bounds__(256) void attn_part_k(const float* __restrict__ mbuf,
    const float* __restrict__ kv, float* __restrict__ part)
{
  __shared__ float red[4][64][26];
  int bh = blockIdx.x;
  int b = bh >> 3, h = bh & 7;
  int chunk = blockIdx.y;
  int wave = threadIdx.x >> 6, lane = threadIdx.x & 63;
  int qq = lane < 49 ? lane : 48;
  float mq[24];
  const float* mp = mbuf + ((size_t)(b*49 + qq)) * 192 + h * 24;
  #pragma unroll
  for (int d = 0; d < 24; d++) mq[d] = mp[d] * SCL;
  float mx = -1e30f, sm = 0.f, acc[24] = {};
  int k0 = chunk * 392 + wave * 98, k1 = k0 + 98;
  for (int key = k0; key < k1; key++) {
    const float* kp = kv + ((size_t)(b*NHW + key)) * 384 + h * 24;
    float s0 = 0.f, s1 = 0.f;
    #pragma unroll
    for (int d = 0; d < 24; d += 2) { s0 += mq[d] * kp[d]; s1 += mq[d+1] * kp[d+1]; }
    float s = s0 + s1;
    float nm = fmaxf(mx, s);
    float f = __expf(mx - nm);
    float p = __expf(s - nm);
    sm = sm * f + p;
    const float* vp = kp + 192;
    #pragma unroll
    for (int d = 0; d < 24; d++) acc[d] = acc[d] * f + p * vp[d];
    mx = nm;
  }
  red[wave][lane][0] = mx;
  red[wave][lane][1] = sm;
  #pragma unroll
  for (int d = 0; d < 24; d++) red[wave][lane][2 + d] = acc[d];
  __syncthreads();
  if (wave == 0 && lane < 49) {
    float gm = -1e30f, gs = 0.f, ga[24] = {};
    #pragma unroll
    for (int w = 0; w < 4; w++) {
      float wm = red[w][lane][0], wsm = red[w][lane][1];
      float nm = fmaxf(gm, wm);
      float f1 = __expf(gm - nm), f2 = __expf(wm - nm);
      gs = gs * f1 + wsm * f2;
      #pragma unroll
      for (int d = 0; d < 24; d++)
        ga[d] = ga[d] * f1 + red[w][lane][2 + d] * f2;
      gm = nm;
    }
    float* pp = part + ((size_t)(bh * 8 + chunk) * 49 + lane) * 26;
    pp[0] = gm; pp[1] = gs;
    #pragma unroll
    for (int d = 0; d < 24; d++) pp[2 + d] = ga[d];
  }
}

// ---------------- attention part 2: merge 8 chunks ----------------
__global__ void attn_merge_k(const float* __restrict__ part, float* __restrict__ obuf)
{
  int bh = blockIdx.x;
  int b = bh >> 3, h = bh & 7;
  int lane = threadIdx.x;
  if (lane >= 49) return;
  float gm = -1e30f, gs = 0.f, ga[24] = {};
  #pragma unroll
  for (int c = 0; c < 8; c++) {
    const float* pp = part + ((size_t)(bh * 8 + c) * 49 + lane) * 26;
    float wm = pp[0], wsm = pp[1];
    float nm = fmaxf(gm, wm);
    float f1 = __expf(gm - nm), f2 = __expf(wm - nm);
    gs = gs * f1 + wsm * f2;
    #pragma unroll
    for (int d = 0; d < 24; d++) ga[d] = ga[d] * f1 + pp[2 + d] * f2;
    gm = nm;
  }
  float inv = 1.0f / gs;
  float* op = obuf + ((size_t)b * 192 + h * 24) * 49 + lane;
  #pragma unroll
  for (int d = 0; d < 24; d++) op[d * 49] = ga[d] * inv;
}

// ---------------- bilinear 7x7 -> 56x56 upsample into cat[:,384:576] ----------------
__global__ __launch_bounds__(256) void upsample_k(const float* __restrict__ obuf,
    float* __restrict__ cat)
{
  int idx = blockIdx.x * 256 + threadIdx.x;
  if (idx >= NB * NHW * CH2) return;
  int c = idx % CH2;
  int pos = idx / CH2;
  int x = pos % 56, y = (pos / 56) % 56, b = pos / NHW;
  float sy = (y + 0.5f) * 0.125f - 0.5f;
  float sx = (x + 0.5f) * 0.125f - 0.5f;
  int y0 = (int)floorf(sy); float ty = sy - (float)y0;
  int x0 = (int)floorf(sx); float tx = sx - (float)x0;
  int y0c = max(y0, 0), y1c = min(y0 + 1, 6);
  int x0c = max(x0, 0), x1c = min(x0 + 1, 6);
  const float* ob = obuf + ((size_t)b * 192 + c) * 49;
  float v = (1.f - ty) * ((1.f - tx) * ob[y0c*7 + x0c] + tx * ob[y0c*7 + x1c])
          +        ty  * ((1.f - tx) * ob[y1c*7 + x0c] + tx * ob[y1c*7 + x1c]);
  cat[(size_t)pos * 768 + 384 + c] = v;
}

extern "C" void kernel_launch(void* const* d_in, const int* in_sizes, int n_in,
                              void* d_out, int out_size, void* d_ws, size_t ws_size,
                              hipStream_t stream) {
  const float* x       = (const float*)d_in[0];
  const float* x_e     = (const float*)d_in[1];
  const float* norm_w  = (const float*)d_in[2];
  const float* norm_b  = (const float*)d_in[3];
  const float* norme_w = (const float*)d_in[4];
  const float* norme_b = (const float*)d_in[5];
  const float* q_w     = (const float*)d_in[6];
  const float* q_b     = (const float*)d_in[7];
  const float* qcut_w  = (const float*)d_in[8];
  const float* qcut_b  = (const float*)d_in[9];
  const float* a_w     = (const float*)d_in[10];
  const float* a_b     = (const float*)d_in[11];
  const float* l_w     = (const float*)d_in[12];
  const float* l_b     = (const float*)d_in[13];
  const float* conv_w  = (const float*)d_in[14];
  const float* conv_b  = (const float*)d_in[15];
  const float* econv_w = (const float*)d_in[16];
  const float* econv_b = (const float*)d_in[17];
  const float* efore_w = (const float*)d_in[18];
  const float* efore_b = (const float*)d_in[19];
  const float* eback_w = (const float*)d_in[20];
  const float* eback_b = (const float*)d_in[21];
  const float* kv_w    = (const float*)d_in[22];
  const float* kv_b    = (const float*)d_in[23];
  const float* scl_w   = (const float*)d_in[24];
  const float* scl_b   = (const float*)d_in[25];
  const float* proj_w  = (const float*)d_in[26];
  const float* proj_b  = (const float*)d_in[27];
  const float* proje_w = (const float*)d_in[28];
  const float* proje_b = (const float*)d_in[29];
  float* out = (float*)d_out;

  float* ws = (float*)d_ws;
  float* xn     = ws;                       // 19267584
  float* xen    = xn  + 19267584;           //  9633792
  float* lx     = xen + 9633792;            // 19267584
  float* kvbuf  = lx  + 19267584;           // 19267584
  float* cat    = kvbuf + 19267584;         // 38535168
  float* pooled = cat + 38535168;           //   451584
  float* mbuf   = pooled + 451584;          //   150528
  float* obuf   = mbuf + 150528;            //   150528
  float* part   = obuf + 150528;            //  1304576 (128*8*49*26)
  float* convbuf  = xn;                     // reuse after xn consumed
  float* efbuf    = lx;                     // reuse after kv gemm
  float* econvbuf = kvbuf;                  // reuse after attention

  // 1-2: LayerNorms
  ln_k<384><<<NROWS/4, 256, 0, stream>>>(x,   norm_w,  norm_b,  xn);
  ln_k<192><<<NROWS/4, 256, 0, stream>>>(x_e, norme_w, norme_b, xen);
  // 3: pool, 4: m = pooled @ scl_w
  pool_k<<<NB*49, 576, 0, stream>>>(xn, xen, pooled);
  gemm_k<0><<<dim3(2, 4), 256, 0, stream>>>(pooled, 576, scl_w, 192, scl_b,
                                            mbuf, 192, 784, 192, 576);
  // 5: q -> cat[:, :384]
  gemm_k<0><<<dim3(3, 196), 256, 0, stream>>>(xn, 384, q_w, 384, q_b,
                                              cat, 768, NROWS, 384, 384);
  // 6: cut -> cat[:, 576:768]
  gemm_k<0><<<dim3(2, 196), 256, 0, stream>>>(xn, 384, qcut_w, 192, qcut_b,
                                              cat + 576, 768, NROWS, 192, 384);
  // 7: lx = gelu(xn @ l_w + l_b)
  gemm_k<1><<<dim3(3, 196), 256, 0, stream>>>(xn, 384, l_w, 384, l_b,
                                              lx, 384, NROWS, 384, 384);
  // 8: dwconv(lx) -> convbuf ; 9: cat_g *= (convbuf @ a_w + a_b)
  dwconv_k<384><<<dim3(49, 6, NB), 256, 0, stream>>>(lx, conv_w, conv_b, convbuf);
  gemm_k<2><<<dim3(3, 196), 256, 0, stream>>>(convbuf, 384, a_w, 384, a_b,
                                              cat, 768, NROWS, 384, 384);
  // 10: kv = lx @ kv_w + kv_b
  gemm_k<0><<<dim3(3, 196), 256, 0, stream>>>(lx, 384, kv_w, 384, kv_b,
                                              kvbuf, 384, NROWS, 384, 384);
  // 11: attention -> obuf ; 12: upsample -> cat[:,384:576]
  attn_part_k<<<dim3(NB*8, 8), 256, 0, stream>>>(mbuf, kvbuf, part);
  attn_merge_k<<<NB*8, 64, 0, stream>>>(part, obuf);
  upsample_k<<<(NB*NHW*CH2)/256, 256, 0, stream>>>(obuf, cat);
  // 13: ef = xen @ efore_w ; 14: dwconv ; 15: cat_cut *= (econv @ eback_w + eback_b)
  gemm_k<0><<<dim3(2, 196), 256, 0, stream>>>(xen, 192, efore_w, 192, efore_b,
                                              efbuf, 192, NROWS, 192, 192);
  dwconv_k<192><<<dim3(49, 3, NB), 256, 0, stream>>>(efbuf, econv_w, econv_b, econvbuf);
  gemm_k<2><<<dim3(2, 196), 256, 0, stream>>>(econvbuf, 192, eback_w, 192, eback_b,
                                              cat + 576, 768, NROWS, 192, 192);
  // 16-17: projections
  gemm_k<0><<<dim3(3, 196), 256, 0, stream>>>(cat, 768, proj_w, 384, proj_b,
                                              out, 384, NROWS, 384, 768);
  gemm_k<0><<<dim3(2, 196), 256, 0, stream>>>(cat, 768, proje_w, 192, proje_b,
                                              out + 19267584, 192, NROWS, 192, 768);
}

// Round 4
// 1585.181 us; speedup vs baseline: 2.3522x; 2.3522x over previous
//
#include <hip/hip_runtime.h>
#include <math.h>

#define NB 16
#define NHW 3136
#define NROWS 50176          // 16*56*56
#define CD 384
#define CH2 192
#define SCL 0.20412414523193154f   // 24^-0.5

typedef short bf16x8 __attribute__((ext_vector_type(8)));
typedef float f32x4 __attribute__((ext_vector_type(4)));
typedef unsigned short ushort;

static __device__ __forceinline__ float gelu_exact(float v) {
  return 0.5f * v * (1.0f + erff(v * 0.70710678118654752440f));
}
static __device__ __forceinline__ ushort f2bf(float f) {
  unsigned u = __builtin_bit_cast(unsigned, f);
  u += 0x7fffu + ((u >> 16) & 1u);
  return (ushort)(u >> 16);
}
static __device__ __forceinline__ float bf2f(ushort h) {
  unsigned u = ((unsigned)h) << 16;
  return __builtin_bit_cast(float, u);
}

// ---------------- LayerNorm -> bf16 hi/lo planes ----------------
template<int CN>
__global__ __launch_bounds__(256) void ln_k(const float* __restrict__ x,
    const float* __restrict__ w, const float* __restrict__ b,
    ushort* __restrict__ oh, ushort* __restrict__ ol)
{
  constexpr int NPER = CN / 64;
  int wave = threadIdx.x >> 6, lane = threadIdx.x & 63;
  int row = blockIdx.x * 4 + wave;
  const float* xp = x + (size_t)row * CN;
  float v[NPER];
  float s = 0.f;
  #pragma unroll
  for (int i = 0; i < NPER; i++) { v[i] = xp[lane + 64*i]; s += v[i]; }
  #pragma unroll
  for (int off = 32; off; off >>= 1) s += __shfl_xor(s, off);
  float mean = s * (1.0f / CN);
  float vs = 0.f;
  #pragma unroll
  for (int i = 0; i < NPER; i++) { float d = v[i] - mean; vs += d*d; }
  #pragma unroll
  for (int off = 32; off; off >>= 1) vs += __shfl_xor(vs, off);
  float rstd = rsqrtf(vs * (1.0f / CN) + 1e-6f);
  #pragma unroll
  for (int i = 0; i < NPER; i++) {
    int c = lane + 64*i;
    float y = (v[i] - mean) * rstd * w[c] + b[c];
    ushort h = f2bf(y);
    oh[(size_t)row * CN + c] = h;
    ol[(size_t)row * CN + c] = f2bf(y - bf2f(h));
  }
}

// ---------------- weight transpose + split: W[K][N] fp32 -> Wh/Wl [Npad][K] bf16 ----------------
__global__ __launch_bounds__(256) void wcvt_k(const float* __restrict__ W,
    int K, int N, ushort* __restrict__ Wh, ushort* __restrict__ Wl)
{
  __shared__ float tl[32][33];
  int k0 = blockIdx.x * 32, n0 = blockIdx.y * 32;
  int r = threadIdx.x >> 5, c = threadIdx.x & 31;
  #pragma unroll
  for (int i = 0; i < 4; i++) {
    int kk = r + 8*i;
    float v = (n0 + c < N) ? W[(size_t)(k0 + kk) * N + n0 + c] : 0.f;
    tl[kk][c] = v;
  }
  __syncthreads();
  #pragma unroll
  for (int i = 0; i < 4; i++) {
    int n = n0 + r + 8*i;
    float v = tl[c][r + 8*i];
    ushort h = f2bf(v);
    Wh[(size_t)n * K + k0 + c] = h;
    Wl[(size_t)n * K + k0 + c] = f2bf(v - bf2f(h));
  }
}

// ---------------- 8x8 average pool of concat(xn, xen) planes ----------------
__global__ void pool_k(const ushort* __restrict__ xnh, const ushort* __restrict__ xnl,
                       const ushort* __restrict__ xeh, const ushort* __restrict__ xel,
                       float* __restrict__ pooled)
{
  int c = threadIdx.x;           // 0..575
  int blk = blockIdx.x;          // 0..783
  int b = blk / 49, q = blk % 49;
  int py = q / 7, px = q % 7;
  float s = 0.f;
  if (c < CD) {
    size_t base = (((size_t)(b*56 + py*8))*56 + px*8) * CD + c;
    #pragma unroll
    for (int iy = 0; iy < 8; iy++)
      for (int ix = 0; ix < 8; ix++) {
        size_t o = base + (size_t)(iy*56 + ix) * CD;
        s += bf2f(xnh[o]) + bf2f(xnl[o]);
      }
  } else {
    int cc = c - CD;
    size_t base = (((size_t)(b*56 + py*8))*56 + px*8) * CH2 + cc;
    #pragma unroll
    for (int iy = 0; iy < 8; iy++)
      for (int ix = 0; ix < 8; ix++) {
        size_t o = base + (size_t)(iy*56 + ix) * CH2;
        s += bf2f(xeh[o]) + bf2f(xel[o]);
      }
  }
  pooled[(size_t)blk * 576 + c] = s * (1.0f / 64.0f);
}

// ---------------- fp32 tiled GEMM (R1 version, only for tiny scl GEMM) ----------------
__global__ __launch_bounds__(256) void gemm_k(
    const float* __restrict__ A, int lda,
    const float* __restrict__ B, int ldb,
    const float* __restrict__ bias,
    float* __restrict__ C, int ldc,
    int M, int N, int K)
{
  __shared__ float As[16][128 + 4];
  __shared__ float Bs[16][64 + 4];
  const int tid = threadIdx.x;
  const int tx = tid & 15;
  const int ty = tid >> 4;
  const int mbase = blockIdx.y * 128;
  const int nbase = blockIdx.x * 64;
  float acc[8][4] = {};
  for (int k0 = 0; k0 < K; k0 += 16) {
    #pragma unroll
    for (int r = 0; r < 2; r++) {
      int idx = tid + r * 256;
      int m = idx >> 2;
      int kq = (idx & 3) * 4;
      float4 av = {0.f, 0.f, 0.f, 0.f};
      if (mbase + m < M)
        av = *reinterpret_cast<const float4*>(&A[(size_t)(mbase + m) * lda + k0 + kq]);
      As[kq + 0][m] = av.x; As[kq + 1][m] = av.y;
      As[kq + 2][m] = av.z; As[kq + 3][m] = av.w;
    }
    {
      int k = tid >> 4;
      int nq = (tid & 15) * 4;
      float4 bv = *reinterpret_cast<const float4*>(&B[(size_t)(k0 + k) * ldb + nbase + nq]);
      *reinterpret_cast<float4*>(&Bs[k][nq]) = bv;
    }
    __syncthreads();
    #pragma unroll
    for (int k = 0; k < 16; k++) {
      float a0[8], b0[4];
      #pragma unroll
      for (int i = 0; i < 8; i++) a0[i] = As[k][ty*8 + i];
      #pragma unroll
      for (int j = 0; j < 4; j++) b0[j] = Bs[k][tx*4 + j];
      #pragma unroll
      for (int i = 0; i < 8; i++)
        #pragma unroll
        for (int j = 0; j < 4; j++)
          acc[i][j] += a0[i] * b0[j];
    }
    __syncthreads();
  }
  float bv[4];
  #pragma unroll
  for (int j = 0; j < 4; j++) bv[j] = bias[nbase + tx*4 + j];
  #pragma unroll
  for (int i = 0; i < 8; i++) {
    int m = mbase + ty*8 + i;
    if (m < M) {
      float* cp = &C[(size_t)m * ldc + nbase + tx*4];
      #pragma unroll
      for (int j = 0; j < 4; j++) cp[j] = acc[i][j] + bv[j];
    }
  }
}

// ---------------- split-bf16 MFMA GEMM: C = (Ah+Al)@(Bh+Bl)^T_planes + bias ----------------
// A planes [M][K] bf16; B planes TRANSPOSED [Npad][K] bf16. 128x128 tile, 4 waves.
// FLAGS: 1=GELU, 2=MUL (C *= prev planes, in-place), 4=F32OUT (write fp32 Cf)
template<int FLAGS>
__global__ __launch_bounds__(256, 2) void gemm_f3(
    const ushort* __restrict__ Ah, const ushort* __restrict__ Al, int lda,
    const ushort* __restrict__ Bh, const ushort* __restrict__ Bl,
    const float* __restrict__ bias,
    float* __restrict__ Cf, ushort* __restrict__ Ch, ushort* __restrict__ Cl,
    int ldc, int N, int K)
{
  __shared__ __align__(16) ushort lds[4 * 8 * 64 * 8];   // 32 KB, frag-major
  const int t = threadIdx.x;
  const int lane = t & 63, wave = t >> 6;
  const int wm = wave >> 1, wn = wave & 1;
  const int mbase = blockIdx.x * 128, nbase = blockIdx.y * 128;
  const int r = t >> 2, kc = t & 3;

  f32x4 acc[4][4];
  #pragma unroll
  for (int i = 0; i < 4; i++)
    #pragma unroll
    for (int j = 0; j < 4; j++) acc[i][j] = (f32x4){0.f, 0.f, 0.f, 0.f};

  for (int k0 = 0; k0 < K; k0 += 32) {
    __syncthreads();
    // stage A hi/lo: frag-major layout, conflict-free writes & reads
    #pragma unroll
    for (int p = 0; p < 2; p++) {
      const ushort* src = p ? Al : Ah;
      #pragma unroll
      for (int hh = 0; hh < 2; hh++) {
        int row = hh * 64 + r;
        bf16x8 v = *(const bf16x8*)(src + (size_t)(mbase + row) * lda + k0 + kc * 8);
        int f = row >> 4, l = (row & 15) + kc * 16;
        *(bf16x8*)&lds[((p * 8 + f) * 64 + l) * 8] = v;
      }
    }
    // stage B hi/lo (already [n][k])
    #pragma unroll
    for (int p = 0; p < 2; p++) {
      const ushort* src = p ? Bl : Bh;
      #pragma unroll
      for (int hh = 0; hh < 2; hh++) {
        int row = hh * 64 + r;
        bf16x8 v = *(const bf16x8*)(src + (size_t)(nbase + row) * K + k0 + kc * 8);
        int f = row >> 4, l = (row & 15) + kc * 16;
        *(bf16x8*)&lds[(((2 + p) * 8 + f) * 64 + l) * 8] = v;
      }
    }
    __syncthreads();
    bf16x8 ah[4], al_[4], bh[4], bl_[4];
    #pragma unroll
    for (int i = 0; i < 4; i++) {
      ah[i]  = *(const bf16x8*)&lds[((0 * 8 + wm * 4 + i) * 64 + lane) * 8];
      al_[i] = *(const bf16x8*)&lds[((1 * 8 + wm * 4 + i) * 64 + lane) * 8];
      bh[i]  = *(const bf16x8*)&lds[((2 * 8 + wn * 4 + i) * 64 + lane) * 8];
      bl_[i] = *(const bf16x8*)&lds[((3 * 8 + wn * 4 + i) * 64 + lane) * 8];
    }
    #pragma unroll
    for (int mi = 0; mi < 4; mi++)
      #pragma unroll
      for (int ni = 0; ni < 4; ni++) {
        acc[mi][ni] = __builtin_amdgcn_mfma_f32_16x16x32_bf16(ah[mi],  bh[ni],  acc[mi][ni], 0, 0, 0);
        acc[mi][ni] = __builtin_amdgcn_mfma_f32_16x16x32_bf16(ah[mi],  bl_[ni], acc[mi][ni], 0, 0, 0);
        acc[mi][ni] = __builtin_amdgcn_mfma_f32_16x16x32_bf16(al_[mi], bh[ni],  acc[mi][ni], 0, 0, 0);
      }
  }

  // epilogue: C/D layout col=lane&15, row=(lane>>4)*4+reg (m89-verified)
  #pragma unroll
  for (int ni = 0; ni < 4; ni++) {
    int col = nbase + wn * 64 + ni * 16 + (lane & 15);
    if (col >= N) continue;
    float bv = bias[col];
    #pragma unroll
    for (int mi = 0; mi < 4; mi++) {
      int row0 = mbase + wm * 64 + mi * 16 + ((lane >> 4) << 2);
      #pragma unroll
      for (int rr = 0; rr < 4; rr++) {
        size_t off = (size_t)(row0 + rr) * ldc + col;
        float v = acc[mi][ni][rr] + bv;
        if (FLAGS & 2) v = (bf2f(Ch[off]) + bf2f(Cl[off])) * v;
        if (FLAGS & 1) v = gelu_exact(v);
        if (FLAGS & 4) {
          Cf[off] = v;
        } else {
          ushort h = f2bf(v);
          Ch[off] = h;
          Cl[off] = f2bf(v - bf2f(h));
        }
      }
    }
  }
}

// ---------------- depthwise 7x7 conv, pad 3, NHWC, bf16-plane in/out ----------------
template<int CH>
__global__ __launch_bounds__(256) void dwconv_k(const ushort* __restrict__ inh,
    const ushort* __restrict__ inl,
    const float* __restrict__ wgt, const float* __restrict__ bias,
    ushort* __restrict__ outh, ushort* __restrict__ outl)
{
  __shared__ float in_t[196 * 64];
  __shared__ float wlds[64 * 49];

  const int t = threadIdx.x;
  const int c = t & 63;
  const int pg = t >> 6;
  const int tile = blockIdx.x;       // 0..48
  const int cbase = blockIdx.y * 64;
  const int b = blockIdx.z;
  const int oy0 = (tile / 7) * 8;
  const int ox0 = (tile % 7) * 8;

  #pragma unroll 7
  for (int i = 0; i < 49; i++) {
    int p = pg + 4 * i;
    int iy = p / 14, ix = p % 14;
    int gy = oy0 + iy - 3;
    int gx = ox0 + ix - 3;
    float v = 0.f;
    if ((unsigned)gy < 56u && (unsigned)gx < 56u) {
      size_t gidx = ((size_t)(b * 56 + gy) * 56 + gx) * CH + cbase + c;
      v = bf2f(inh[gidx]) + bf2f(inl[gidx]);
    }
    in_t[p * 64 + c] = v;
  }
  #pragma unroll
  for (int i = 0; i < 13; i++) {
    int j = t + 256 * i;
    if (j < 64 * 49) wlds[j] = wgt[(size_t)cbase * 49 + j];
  }
  __syncthreads();

  float bv = bias[cbase + c];
  float acc[2][8];
  #pragma unroll
  for (int r = 0; r < 2; r++)
    #pragma unroll
    for (int x = 0; x < 8; x++) acc[r][x] = bv;

  #pragma unroll
  for (int dy = 0; dy < 7; dy++) {
    float wrow[7];
    #pragma unroll
    for (int dx = 0; dx < 7; dx++) wrow[dx] = wlds[c * 49 + dy * 7 + dx];
    #pragma unroll
    for (int r = 0; r < 2; r++) {
      int oy = pg * 2 + r;
      int iy = oy + dy;
      float win[14];
      #pragma unroll
      for (int j = 0; j < 14; j++) win[j] = in_t[(iy * 14 + j) * 64 + c];
      #pragma unroll
      for (int dx = 0; dx < 7; dx++)
        #pragma unroll
        for (int x = 0; x < 8; x++)
          acc[r][x] += win[x + dx] * wrow[dx];
    }
  }

  #pragma unroll
  for (int r = 0; r < 2; r++) {
    int oy = pg * 2 + r;
    #pragma unroll
    for (int x = 0; x < 8; x++) {
      size_t oidx = ((size_t)(b * 56 + oy0 + oy) * 56 + ox0 + x) * CH + cbase + c;
      float val = acc[r][x];
      ushort h = f2bf(val);
      outh[oidx] = h;
      outl[oidx] = f2bf(val - bf2f(h));
    }
  }
}

// ---------------- attention part 1: per-chunk online softmax partials ----------------
__global__ __launch_bounds__(256) void attn_part_k(const float* __restrict__ mbuf,
    const float* __restrict__ kv, float* __restrict__ part)
{
  __shared__ float red[4][64][26];
  int bh = blockIdx.x;
  int b = bh >> 3, h = bh & 7;
  int chunk = blockIdx.y;
  int wave = threadIdx.x >> 6, lane = threadIdx.x & 63;
  int qq = lane < 49 ? lane : 48;
  float mq[24];
  const float* mp = mbuf + ((size_t)(b*49 + qq)) * 192 + h * 24;
  #pragma unroll
  for (int d = 0; d < 24; d++) mq[d] = mp[d] * SCL;
  float mx = -1e30f, sm = 0.f, acc[24] = {};
  int k0 = chunk * 392 + wave * 98, k1 = k0 + 98;
  for (int key = k0; key < k1; key++) {
    const float* kp = kv + ((size_t)(b*NHW + key)) * 384 + h * 24;
    float s0 = 0.f, s1 = 0.f;
    #pragma unroll
    for (int d = 0; d < 24; d += 2) { s0 += mq[d] * kp[d]; s1 += mq[d+1] * kp[d+1]; }
    float s = s0 + s1;
    float nm = fmaxf(mx, s);
    float f = __expf(mx - nm);
    float p = __expf(s - nm);
    sm = sm * f + p;
    const float* vp = kp + 192;
    #pragma unroll
    for (int d = 0; d < 24; d++) acc[d] = acc[d] * f + p * vp[d];
    mx = nm;
  }
  red[wave][lane][0] = mx;
  red[wave][lane][1] = sm;
  #pragma unroll
  for (int d = 0; d < 24; d++) red[wave][lane][2 + d] = acc[d];
  __syncthreads();
  if (wave == 0 && lane < 49) {
    float gm = -1e30f, gs = 0.f, ga[24] = {};
    #pragma unroll
    for (int w = 0; w < 4; w++) {
      float wm = red[w][lane][0], wsm = red[w][lane][1];
      float nm = fmaxf(gm, wm);
      float f1 = __expf(gm - nm), f2 = __expf(wm - nm);
      gs = gs * f1 + wsm * f2;
      #pragma unroll
      for (int d = 0; d < 24; d++)
        ga[d] = ga[d] * f1 + red[w][lane][2 + d] * f2;
      gm = nm;
    }
    float* pp = part + ((size_t)(bh * 8 + chunk) * 49 + lane) * 26;
    pp[0] = gm; pp[1] = gs;
    #pragma unroll
    for (int d = 0; d < 24; d++) pp[2 + d] = ga[d];
  }
}

// ---------------- attention part 2: merge 8 chunks ----------------
__global__ void attn_merge_k(const float* __restrict__ part, float* __restrict__ obuf)
{
  int bh = blockIdx.x;
  int b = bh >> 3, h = bh & 7;
  int lane = threadIdx.x;
  if (lane >= 49) return;
  float gm = -1e30f, gs = 0.f, ga[24] = {};
  #pragma unroll
  for (int c = 0; c < 8; c++) {
    const float* pp = part + ((size_t)(bh * 8 + c) * 49 + lane) * 26;
    float wm = pp[0], wsm = pp[1];
    float nm = fmaxf(gm, wm);
    float f1 = __expf(gm - nm), f2 = __expf(wm - nm);
    gs = gs * f1 + wsm * f2;
    #pragma unroll
    for (int d = 0; d < 24; d++) ga[d] = ga[d] * f1 + pp[2 + d] * f2;
    gm = nm;
  }
  float inv = 1.0f / gs;
  float* op = obuf + ((size_t)b * 192 + h * 24) * 49 + lane;
  #pragma unroll
  for (int d = 0; d < 24; d++) op[d * 49] = ga[d] * inv;
}

// ---------------- bilinear 7x7 -> 56x56 upsample into cat planes cols[384,576) ----------------
__global__ __launch_bounds__(256) void upsample_k(const float* __restrict__ obuf,
    ushort* __restrict__ cath, ushort* __restrict__ catl)
{
  int idx = blockIdx.x * 256 + threadIdx.x;
  if (idx >= NB * NHW * CH2) return;
  int c = idx % CH2;
  int pos = idx / CH2;
  int x = pos % 56, y = (pos / 56) % 56, b = pos / NHW;
  float sy = (y + 0.5f) * 0.125f - 0.5f;
  float sx = (x + 0.5f) * 0.125f - 0.5f;
  int y0 = (int)floorf(sy); float ty = sy - (float)y0;
  int x0 = (int)floorf(sx); float tx = sx - (float)x0;
  int y0c = max(y0, 0), y1c = min(y0 + 1, 6);
  int x0c = max(x0, 0), x1c = min(x0 + 1, 6);
  const float* ob = obuf + ((size_t)b * 192 + c) * 49;
  float v = (1.f - ty) * ((1.f - tx) * ob[y0c*7 + x0c] + tx * ob[y0c*7 + x1c])
          +        ty  * ((1.f - tx) * ob[y1c*7 + x0c] + tx * ob[y1c*7 + x1c]);
  size_t off = (size_t)pos * 768 + 384 + c;
  ushort h = f2bf(v);
  cath[off] = h;
  catl[off] = f2bf(v - bf2f(h));
}

extern "C" void kernel_launch(void* const* d_in, const int* in_sizes, int n_in,
                              void* d_out, int out_size, void* d_ws, size_t ws_size,
                              hipStream_t stream) {
  const float* x       = (const float*)d_in[0];
  const float* x_e     = (const float*)d_in[1];
  const float* norm_w  = (const float*)d_in[2];
  const float* norm_b  = (const float*)d_in[3];
  const float* norme_w = (const float*)d_in[4];
  const float* norme_b = (const float*)d_in[5];
  const float* q_w     = (const float*)d_in[6];
  const float* q_b     = (const float*)d_in[7];
  const float* qcut_w  = (const float*)d_in[8];
  const float* qcut_b  = (const float*)d_in[9];
  const float* a_w     = (const float*)d_in[10];
  const float* a_b     = (const float*)d_in[11];
  const float* l_w     = (const float*)d_in[12];
  const float* l_b     = (const float*)d_in[13];
  const float* conv_w  = (const float*)d_in[14];
  const float* conv_b  = (const float*)d_in[15];
  const float* econv_w = (const float*)d_in[16];
  const float* econv_b = (const float*)d_in[17];
  const float* efore_w = (const float*)d_in[18];
  const float* efore_b = (const float*)d_in[19];
  const float* eback_w = (const float*)d_in[20];
  const float* eback_b = (const float*)d_in[21];
  const float* kv_w    = (const float*)d_in[22];
  const float* kv_b    = (const float*)d_in[23];
  const float* scl_w   = (const float*)d_in[24];
  const float* scl_b   = (const float*)d_in[25];
  const float* proj_w  = (const float*)d_in[26];
  const float* proj_b  = (const float*)d_in[27];
  const float* proje_w = (const float*)d_in[28];
  const float* proje_b = (const float*)d_in[29];
  float* out = (float*)d_out;

  char* w8 = (char*)d_ws;
  const size_t P384B = (size_t)NROWS * 384 * 2;   // 38,535,168
  const size_t P192B = (size_t)NROWS * 192 * 2;   // 19,267,584
  const size_t P768B = (size_t)NROWS * 768 * 2;   // 77,070,336
  size_t o = 0;
  auto alloc = [&](size_t bytes) { size_t r = o; o += (bytes + 255) & ~(size_t)255; return r; };
  size_t xnh_o  = alloc(P384B);
  size_t xnl_o  = alloc(P384B);
  size_t xenh_o = alloc(P192B);
  size_t xenl_o = alloc(P192B);
  size_t lxh_o  = alloc(P384B);
  size_t lxl_o  = alloc(P384B);
  size_t cath_o = alloc(P768B);
  size_t catl_o = alloc(P768B);
  size_t pooled_o = alloc(784 * 576 * 4);
  size_t mbuf_o   = alloc(784 * 192 * 4);
  size_t obuf_o   = alloc((size_t)NB * 192 * 49 * 4);
  size_t part_o   = alloc((size_t)128 * 8 * 49 * 26 * 4);
  // weights: [Npad][K] bf16 hi/lo
  size_t qwh_o  = alloc(384 * 384 * 2), qwl_o  = alloc(384 * 384 * 2);
  size_t qcwh_o = alloc(256 * 384 * 2), qcwl_o = alloc(256 * 384 * 2);
  size_t lwh_o  = alloc(384 * 384 * 2), lwl_o  = alloc(384 * 384 * 2);
  size_t awh_o  = alloc(384 * 384 * 2), awl_o  = alloc(384 * 384 * 2);
  size_t kvwh_o = alloc(384 * 384 * 2), kvwl_o = alloc(384 * 384 * 2);
  size_t efwh_o = alloc(256 * 192 * 2), efwl_o = alloc(256 * 192 * 2);
  size_t ebwh_o = alloc(256 * 192 * 2), ebwl_o = alloc(256 * 192 * 2);
  size_t pjwh_o = alloc(384 * 768 * 2), pjwl_o = alloc(384 * 768 * 2);
  size_t pjewh_o = alloc(256 * 768 * 2), pjewl_o = alloc(256 * 768 * 2);

  auto U = [&](size_t off) { return (ushort*)(w8 + off); };
  auto F = [&](size_t off) { return (float*)(w8 + off); };

  ushort *xnh = U(xnh_o), *xnl = U(xnl_o), *xenh = U(xenh_o), *xenl = U(xenl_o);
  ushort *lxh = U(lxh_o), *lxl = U(lxl_o);
  ushort *cath = U(cath_o), *catl = U(catl_o);
  float *pooled = F(pooled_o), *mbuf = F(mbuf_o), *obuf = F(obuf_o), *part = F(part_o);
  // aliases (sequenced reuse)
  ushort *convh = xnh, *convl = xnl;                 // after l-gemm, xn planes dead
  float  *kvbuf = F(xnh_o);                          // fp32, 77MB over xn region (conv dead)
  ushort *econvh = U(xnh_o), *econvl = U(xnh_o + P192B); // after attn, kvbuf dead
  ushort *efh = lxh, *efl = lxl;                     // after kv-gemm, lx planes dead

  // 0: weight conversions (transpose + bf16 split)
  wcvt_k<<<dim3(12, 12), 256, 0, stream>>>(q_w,     384, 384, U(qwh_o),  U(qwl_o));
  wcvt_k<<<dim3(12,  8), 256, 0, stream>>>(qcut_w,  384, 192, U(qcwh_o), U(qcwl_o));
  wcvt_k<<<dim3(12, 12), 256, 0, stream>>>(l_w,     384, 384, U(lwh_o),  U(lwl_o));
  wcvt_k<<<dim3(12, 12), 256, 0, stream>>>(a_w,     384, 384, U(awh_o),  U(awl_o));
  wcvt_k<<<dim3(12, 12), 256, 0, stream>>>(kv_w,    384, 384, U(kvwh_o), U(kvwl_o));
  wcvt_k<<<dim3( 6,  8), 256, 0, stream>>>(efore_w, 192, 192, U(efwh_o), U(efwl_o));
  wcvt_k<<<dim3( 6,  8), 256, 0, stream>>>(eback_w, 192, 192, U(ebwh_o), U(ebwl_o));
  wcvt_k<<<dim3(24, 12), 256, 0, stream>>>(proj_w,  768, 384, U(pjwh_o), U(pjwl_o));
  wcvt_k<<<dim3(24,  8), 256, 0, stream>>>(proje_w, 768, 192, U(pjewh_o), U(pjewl_o));

  // 1-2: LayerNorms -> bf16 planes
  ln_k<384><<<NROWS/4, 256, 0, stream>>>(x,   norm_w,  norm_b,  xnh, xnl);
  ln_k<192><<<NROWS/4, 256, 0, stream>>>(x_e, norme_w, norme_b, xenh, xenl);
  // 3: pool, 4: m = pooled @ scl_w (tiny fp32 GEMM)
  pool_k<<<NB*49, 576, 0, stream>>>(xnh, xnl, xenh, xenl, pooled);
  gemm_k<<<dim3(3, 7), 256, 0, stream>>>(pooled, 576, scl_w, 192, scl_b,
                                         mbuf, 192, 784, 192, 576);
  // 5: q -> cat planes cols [0,384)
  gemm_f3<0><<<dim3(392, 3), 256, 0, stream>>>(xnh, xnl, 384, U(qwh_o), U(qwl_o), q_b,
                                               nullptr, cath, catl, 768, 384, 384);
  // 6: cut -> cat planes cols [576,768)
  gemm_f3<0><<<dim3(392, 2), 256, 0, stream>>>(xnh, xnl, 384, U(qcwh_o), U(qcwl_o), qcut_b,
                                               nullptr, cath + 576, catl + 576, 768, 192, 384);
  // 7: lx = gelu(xn @ l_w + l_b) -> planes
  gemm_f3<1><<<dim3(392, 3), 256, 0, stream>>>(xnh, xnl, 384, U(lwh_o), U(lwl_o), l_b,
                                               nullptr, lxh, lxl, 384, 384, 384);
  // 8: dwconv(lx) -> conv planes (xn space)
  dwconv_k<384><<<dim3(49, 6, NB), 256, 0, stream>>>(lxh, lxl, conv_w, conv_b, convh, convl);
  // 9: cat_g *= (conv @ a_w + a_b), in place on planes
  gemm_f3<2><<<dim3(392, 3), 256, 0, stream>>>(convh, convl, 384, U(awh_o), U(awl_o), a_b,
                                               nullptr, cath, catl, 768, 384, 384);
  // 10: kv = lx @ kv_w + kv_b -> fp32 kvbuf (overwrites conv planes)
  gemm_f3<4><<<dim3(392, 3), 256, 0, stream>>>(lxh, lxl, 384, U(kvwh_o), U(kvwl_o), kv_b,
                                               kvbuf, nullptr, nullptr, 384, 384, 384);
  // 11: attention -> obuf ; 12: upsample -> cat planes cols [384,576)
  attn_part_k<<<dim3(NB*8, 8), 256, 0, stream>>>(mbuf, kvbuf, part);
  attn_merge_k<<<NB*8, 64, 0, stream>>>(part, obuf);
  upsample_k<<<(NB*NHW*CH2)/256, 256, 0, stream>>>(obuf, cath, catl);
  // 13: ef = xen @ efore_w -> planes (lx space)
  gemm_f3<0><<<dim3(392, 2), 256, 0, stream>>>(xenh, xenl, 192, U(efwh_o), U(efwl_o), efore_b,
                                               nullptr, efh, efl, 192, 192, 192);
  // 14: dwconv(ef) -> econv planes (kvbuf space)
  dwconv_k<192><<<dim3(49, 3, NB), 256, 0, stream>>>(efh, efl, econv_w, econv_b, econvh, econvl);
  // 15: cat_cut *= (econv @ eback_w + eback_b), in place
  gemm_f3<2><<<dim3(392, 2), 256, 0, stream>>>(econvh, econvl, 192, U(ebwh_o), U(ebwl_o), eback_b,
                                               nullptr, cath + 576, catl + 576, 768, 192, 192);
  // 16-17: projections -> fp32 out
  gemm_f3<4><<<dim3(392, 3), 256, 0, stream>>>(cath, catl, 768, U(pjwh_o), U(pjwl_o), proj_b,
                                               out, nullptr, nullptr, 384, 384, 768);
  gemm_f3<4><<<dim3(392, 2), 256, 0, stream>>>(cath, catl, 768, U(pjewh_o), U(pjewl_o), proje_b,
                                               out + (size_t)NROWS * 384, nullptr, nullptr, 192, 192, 768);
}